// Round 5
// baseline (243.702 us; speedup 1.0000x reference)
//
#include <hip/hip_runtime.h>
#include <stdint.h>

// ---------------- workspace layout (bytes) ----------------
#define OFF_EX   ((size_t)0)           // EX[h][64] f32, 32K
#define OFF_EY   ((size_t)32768)       // EY[c2][128] f32, 32K
#define OFF_EXM  ((size_t)65536)       // EXM[r8][64] f32, 2K
#define OFF_EYM  ((size_t)67584)       // EYM[c8][64] f32, 2K
#define OFF_WQB  ((size_t)69632)       // Wq bf16 [128][128], 32K
#define OFF_WPB  ((size_t)102400)      // Wproj bf16 [128][128], 32K
#define OFF_P8   ((size_t)135168)      // pool8(x only) f32 (8,128,64), 256K
#define OFF_KWS  ((size_t)393216)      // K bf16 (8,8,96,16), 192K
#define OFF_VWS  ((size_t)589824)      // V^T bf16 (8,8,16,96), 192K

typedef __attribute__((ext_vector_type(4)))  float f32x4;
typedef __attribute__((ext_vector_type(16))) float f32x16;
typedef __attribute__((ext_vector_type(8)))  short s16x8;
typedef __attribute__((ext_vector_type(4)))  unsigned int u32x4;

__device__ __forceinline__ uint16_t f2bf(float f){
  uint32_t u = __builtin_bit_cast(uint32_t, f);
  u += 0x7fffu + ((u >> 16) & 1u);
  return (uint16_t)(u >> 16);
}
__device__ __forceinline__ uint32_t cvtpk(float a, float b){
  uint32_t r;
  asm("v_cvt_pk_bf16_f32 %0, %1, %2" : "=v"(r) : "v"(a), "v"(b));
  return r;
}

// ---------------- K0: tables + weight bf16 casts (R3-exact) ----------------
__global__ __launch_bounds__(256) void kprep(const float* __restrict__ Wq,
                                             const float* __restrict__ Wproj,
                                             char* __restrict__ ws){
  int idx = blockIdx.x * 256 + threadIdx.x;
  float* EX = (float*)(ws + OFF_EX);
  float* EY = (float*)(ws + OFF_EY);
  float* EXM = (float*)(ws + OFF_EXM);
  float* EYM = (float*)(ws + OFF_EYM);
  uint16_t* WQB = (uint16_t*)(ws + OFF_WQB);
  uint16_t* WPB = (uint16_t*)(ws + OFF_WPB);
  if (idx < 8192){
    int i = idx >> 6, d = idx & 63;
    float inv = powf(10000.0f, -(float)(d & 31) * (1.0f/32.0f));
    float a = (float)i * inv;
    EX[idx] = (d < 32) ? sinf(a) : cosf(a);
  } else if (idx < 16384){
    int e = idx - 8192;
    int c = e >> 7, j = e & 127;
    float inv = powf(10000.0f, -(float)(c & 31) * (1.0f/32.0f));
    float a = (float)j * inv;
    EY[e] = (c < 32) ? sinf(a) : cosf(a);
  } else if (idx < 32768){
    int e = idx - 16384;
    WQB[e] = f2bf(Wq[e]);
  } else if (idx < 49152){
    int e = idx - 32768;
    WPB[e] = f2bf(Wproj[e]);
  } else if (idx < 49664){
    int e = idx - 49152; int r8 = e >> 6, c = e & 63;
    float inv = powf(10000.0f, -(float)(c & 31) * (1.0f/32.0f));
    float s = 0.f;
    for (int u = 0; u < 16; ++u){
      float a = (float)(r8*16 + u) * inv;
      s += (c < 32) ? sinf(a) : cosf(a);
    }
    EXM[e] = s * (1.0f/16.0f);
  } else if (idx < 50176){
    int e = idx - 49664; int c8 = e >> 6, c2 = e & 63;
    float inv = powf(10000.0f, -(float)(c2 & 31) * (1.0f/32.0f));
    float s = 0.f;
    for (int w = 0; w < 16; ++w){
      float a = (float)(c8*16 + w) * inv;
      s += (c2 < 32) ? sinf(a) : cosf(a);
    }
    EYM[e] = s * (1.0f/16.0f);
  }
}

// ---------------- K1: pool8 of raw x (R3-exact) ----------------
__global__ __launch_bounds__(256) void kpool2(const float* __restrict__ x,
                                              char* __restrict__ ws){
  float* P8 = (float*)(ws + OFF_P8);
  int bx = blockIdx.x;
  int b = bx >> 7, c = bx & 127;
  int t = threadIdx.x, lane = t & 63, wv = t >> 6;
  const float* plane = x + ((size_t)(b*128 + c))*16384;
  float acc[8];
  #pragma unroll
  for (int r = 0; r < 8; ++r) acc[r] = 0.f;
  #pragma unroll
  for (int k = 0; k < 16; ++k){
    f32x4 v = *(const f32x4*)(plane + k*1024 + t*4);
    acc[k >> 1] += (v.x + v.y) + (v.z + v.w);
  }
  __shared__ float wred[4][64];
  int bc = (lane >> 2) & 7;
  #pragma unroll
  for (int br = 0; br < 8; ++br){
    float v = acc[br];
    v += __shfl_xor(v, 1);
    v += __shfl_xor(v, 2);
    v += __shfl_xor(v, 32);
    if ((lane & 3) == 0 && lane < 32) wred[wv][br*8 + bc] = v;
  }
  __syncthreads();
  if (t < 64){
    float s = wred[0][t] + wred[1][t] + wred[2][t] + wred[3][t];
    P8[((size_t)(b*128) + c)*64 + t] = s * (1.0f/256.0f);
  }
}

// ---------------- K2: ASPP branch + LN + GELU + KV (R3-exact) ----------------
__global__ __launch_bounds__(256) void kaspp(const float* __restrict__ dww,
                                             const float* __restrict__ pww,
                                             const float* __restrict__ Wkv,
                                             const float* __restrict__ lnw,
                                             const float* __restrict__ lnb,
                                             char* __restrict__ ws){
  const float* P8  = (const float*)(ws + OFF_P8);
  const float* EXM = (const float*)(ws + OFF_EXM);
  const float* EYM = (const float*)(ws + OFF_EYM);
  uint16_t* KWS = (uint16_t*)(ws + OFF_KWS);
  uint16_t* VWS = (uint16_t*)(ws + OFF_VWS);
  int bx = blockIdx.x;
  int b = bx / 96;
  int pos = bx % 96;
  int t = threadIdx.x;

  if (pos >= 85){
    if (t < 128){
      int m = t >> 4, hd = t & 15;
      KWS[(((size_t)b*8 + m)*96 + pos)*16 + hd] = 0;
      VWS[(((size_t)b*8 + m)*16 + hd)*96 + pos] = 0;
    }
    return;
  }

  int s, si, sj;
  if (pos < 64){ s = 8; si = pos >> 3; sj = pos & 7; }
  else if (pos < 80){ int e = pos - 64; s = 4; si = e >> 2; sj = e & 3; }
  else if (pos < 84){ int e = pos - 80; s = 2; si = e >> 1; sj = e & 1; }
  else { s = 1; si = 0; sj = 0; }

  __shared__ float yl[128], zl[128], red[128], red2[128];

  float acc = 0.f;
  if (t < 128){
    int c = t;
    int bs = 8 / s;
    float y = 0.f;
    const float* p8 = P8 + ((size_t)(b*128) + c)*64;
    float binv = 1.0f / (float)(bs*bs);
    for (int di = -1; di <= 1; ++di)
      for (int dj = -1; dj <= 1; ++dj){
        int a = si + di, bb = sj + dj;
        if (a >= 0 && a < s && bb >= 0 && bb < s){
          float pv = 0.f;
          for (int u = 0; u < bs; ++u)
            for (int v = 0; v < bs; ++v){
              int r8 = a*bs + u, c8 = bb*bs + v;
              float pe = (c < 64) ? EXM[r8*64 + c] : EYM[c8*64 + (c - 64)];
              pv += p8[r8*8 + c8] + pe;
            }
          y += pv * binv * dww[c*9 + (di+1)*3 + (dj+1)];
        }
      }
    yl[t] = y;
  }
  __syncthreads();

  if (t < 128){
    const float* wr = pww + (size_t)t*128;
    for (int cin = 0; cin < 128; ++cin) acc += wr[cin] * yl[cin];
    red[t] = acc; red2[t] = acc*acc;
  }
  __syncthreads();
  for (int off = 64; off >= 1; off >>= 1){
    if (t < off){ red[t] += red[t+off]; red2[t] += red2[t+off]; }
    __syncthreads();
  }
  float mu  = red[0] * (1.0f/128.0f);
  float var = red2[0] * (1.0f/128.0f) - mu*mu;
  if (t < 128){
    float z = (acc - mu) * rsqrtf(var + 1e-5f) * lnw[t] + lnb[t];
    zl[t] = 0.5f * z * (1.0f + erff(z * 0.70710678118654752f));
  }
  __syncthreads();

  {
    float a2 = 0.f;
    const float* wr = Wkv + (size_t)t*128;
    for (int c2 = 0; c2 < 128; ++c2) a2 += wr[c2] * zl[c2];
    uint16_t bv = f2bf(a2);
    if (t < 128){
      int m = t >> 4, hd = t & 15;
      KWS[(((size_t)b*8 + m)*96 + pos)*16 + hd] = bv;
    } else {
      int tt = t - 128;
      int m = tt >> 4, hd = tt & 15;
      VWS[(((size_t)b*8 + m)*16 + hd)*96 + pos] = bv;
    }
  }
}

// ---------------- K3: fused stage + q-GEMM + attention + proj ----------------
// 64 pixels / block, 4 waves, LDS 32 KiB -> 5 blocks/CU.
// region A [0,16K): x-tile bf16 [64 pix][256B swz]  -> overwritten by Q (same format)
// region B [16K,32K): f32 tmp [64 cl][64 pix] (per half) -> later O [64 pix][256B swz]
__global__ __launch_bounds__(256, 5) void kmain(const char* __restrict__ wsc,
                                                const float* __restrict__ x,
                                                const float* __restrict__ bproj,
                                                float* __restrict__ out){
  const char* ws = wsc;
  const uint16_t* WQB = (const uint16_t*)(ws + OFF_WQB);
  const uint16_t* WPB = (const uint16_t*)(ws + OFF_WPB);
  const uint16_t* KWS = (const uint16_t*)(ws + OFF_KWS);
  const uint16_t* VWS = (const uint16_t*)(ws + OFF_VWS);
  const float* EX = (const float*)(ws + OFF_EX);
  const float* EY = (const float*)(ws + OFF_EY);

  __shared__ __align__(16) char smem[32768];
  const int t = threadIdx.x;
  const int lane = t & 63;
  const int wv = t >> 6;
  const int bx = blockIdx.x;
  const int b = bx >> 8;
  const int pix0 = (bx & 255) * 64;
  const int i  = pix0 >> 7;
  const int j0 = pix0 & 127;

  // ---- stage 0: x + PE -> bf16 x-tile [pix][c] swz, in two 64-channel halves ----
  #pragma unroll 1
  for (int half = 0; half < 2; ++half){
    // 0a: chans half*64 .. half*64+63 -> f32 tmp [cl][64 pix] @ region B
    {
      int csub = lane >> 4;
      int p4 = (lane & 15) * 4;
      #pragma unroll
      for (int it = 0; it < 4; ++it){
        int cl = wv*16 + it*4 + csub;
        int c = half*64 + cl;
        f32x4 v = *(const f32x4*)(x + ((size_t)(b*128 + c))*16384 + pix0 + p4);
        if (c < 64){
          float pe = EX[i*64 + c];
          v.x += pe; v.y += pe; v.z += pe; v.w += pe;
        } else {
          f32x4 pe = *(const f32x4*)(EY + (c - 64)*128 + j0 + p4);
          v.x += pe.x; v.y += pe.y; v.z += pe.z; v.w += pe.w;
        }
        *(f32x4*)(smem + 16384 + cl*256 + p4*4) = v;
      }
    }
    __syncthreads();
    // 0b: transpose 16 chans/wave -> x-tile @ region A (R3 swz format)
    {
      const float* tmp = (const float*)(smem + 16384);
      int pix = lane;
      float f[16];
      #pragma unroll
      for (int j = 0; j < 16; ++j) f[j] = tmp[(wv*16 + j)*64 + pix];
      uint32_t u[8];
      #pragma unroll
      for (int j = 0; j < 8; ++j) u[j] = cvtpk(f[2*j], f[2*j+1]);
      #pragma unroll
      for (int g = 0; g < 2; ++g){
        u32x4 w4 = { u[g*4+0], u[g*4+1], u[g*4+2], u[g*4+3] };
        int c0 = half*64 + wv*16 + g*8;
        *(u32x4*)(smem + pix*256 + ((c0*2) ^ ((pix & 7) << 4))) = w4;
      }
    }
    __syncthreads();
  }

  // ---- stage 1: q[pix][nq] = Xpe @ Wq^T (R3-exact; Q overwrites x-tile after barrier) ----
  {
    int pixl = wv*16 + (lane & 15);
    s16x8 xfr[4];
    #pragma unroll
    for (int ks = 0; ks < 4; ++ks)
      xfr[ks] = *(const s16x8*)(smem + pixl*256 +
                 ((ks*64 + (lane >> 4)*16) ^ ((pixl & 7) << 4)));
    __syncthreads();   // all waves hold their x-frags; region A may now become Q
    #pragma unroll
    for (int nt = 0; nt < 8; ++nt){
      f32x4 acc = {0.f, 0.f, 0.f, 0.f};
      #pragma unroll
      for (int ks = 0; ks < 4; ++ks){
        s16x8 wfr = *(const s16x8*)(WQB + (nt*16 + (lane & 15))*128 + ks*32 + 8*(lane >> 4));
        acc = __builtin_amdgcn_mfma_f32_16x16x32_bf16(wfr, xfr[ks], acc, 0, 0, 0);
      }
      int nq0 = nt*16 + 4*(lane >> 4);
      uint32_t w0 = cvtpk(acc[0], acc[1]);
      uint32_t w1 = cvtpk(acc[2], acc[3]);
      *(uint32_t*)(smem + pixl*256 + ((nq0*2) ^ ((pixl & 7) << 4))) = w0;
      *(uint32_t*)(smem + pixl*256 + (((nq0 + 2)*2) ^ ((pixl & 7) << 4))) = w1;
    }
  }
  __syncthreads();

  // ---- stage 2: attention, P fully in-register (R3-exact) ----
  {
    const int ph = wv & 1;
    const int h0 = (wv >> 1) * 4;
    const int hi = lane >> 5;
    const int pixq = ph*32 + (lane & 31);
    const float C1 = 0.36067376022224085f; // 0.25 * log2(e)

    #pragma unroll 1
    for (int h = h0; h < h0 + 4; ++h){
      const uint16_t* Kh = KWS + ((size_t)(b*8 + h))*1536;
      const uint16_t* Vh = VWS + ((size_t)(b*8 + h))*1536;
      s16x8 kf[3], vf[6];
      #pragma unroll
      for (int mt = 0; mt < 3; ++mt)
        kf[mt] = *(const s16x8*)(Kh + (mt*32 + (lane & 31))*16 + 8*hi);
      #pragma unroll
      for (int kc = 0; kc < 6; ++kc)
        vf[kc] = *(const s16x8*)(Vh + (lane & 15)*96 + kc*16 + 8*hi);
      s16x8 qf = *(const s16x8*)(smem + pixq*256 + ((h*32 + hi*16) ^ ((pixq & 7) << 4)));

      f32x16 zz;
      #pragma unroll
      for (int r = 0; r < 16; ++r) zz[r] = 0.f;
      f32x16 sa[3];
      #pragma unroll
      for (int mt = 0; mt < 3; ++mt)
        sa[mt] = __builtin_amdgcn_mfma_f32_32x32x16_bf16(kf[mt], qf, zz, 0, 0, 0);

      // softmax over kv (invalid kv scores are exactly 0 -> mx >= 0 is safe)
      float mx = 0.f;
      #pragma unroll
      for (int r = 0; r < 16; ++r){
        mx = fmaxf(mx, sa[0][r]);
        mx = fmaxf(mx, sa[1][r]);
        mx = fmaxf(mx, sa[2][r]);
      }
      mx = fmaxf(mx, __shfl_xor(mx, 32));
      float sum = 0.f;
      #pragma unroll
      for (int r = 0; r < 16; ++r){
        float p0 = exp2f((sa[0][r] - mx)*C1); sa[0][r] = p0; sum += p0;
        float p1 = exp2f((sa[1][r] - mx)*C1); sa[1][r] = p1; sum += p1;
        int kvb = (r & 3) + 8*(r >> 2) + 4*hi;
        float p2 = (64 + kvb < 85) ? exp2f((sa[2][r] - mx)*C1) : 0.f;
        sa[2][r] = p2; sum += p2;
      }
      sum += __shfl_xor(sum, 32);
      float rinv = 1.0f / sum;

      // PV: pack P (unnormalized) via cvt_pk + one lane^32 exchange
      f32x16 oacc = zz;
      #pragma unroll
      for (int mt = 0; mt < 3; ++mt){
        uint32_t u0[4], u1[4];
        #pragma unroll
        for (int q = 0; q < 4; ++q){
          u0[q] = cvtpk(sa[mt][4*q + 0], sa[mt][4*q + 1]);
          u1[q] = cvtpk(sa[mt][4*q + 2], sa[mt][4*q + 3]);
        }
        #pragma unroll
        for (int c2 = 0; c2 < 2; ++c2){
          uint32_t s0 = hi ? u0[2*c2] : u0[2*c2 + 1];
          uint32_t s1 = hi ? u1[2*c2] : u1[2*c2 + 1];
          uint32_t r0 = (uint32_t)__shfl_xor((int)s0, 32);
          uint32_t r1 = (uint32_t)__shfl_xor((int)s1, 32);
          u32x4 w4;
          w4.x = hi ? r0 : u0[2*c2];
          w4.y = hi ? r1 : u1[2*c2];
          w4.z = hi ? u0[2*c2 + 1] : r0;
          w4.w = hi ? u1[2*c2 + 1] : r1;
          oacc = __builtin_amdgcn_mfma_f32_32x32x16_bf16(
                   vf[mt*2 + c2], __builtin_bit_cast(s16x8, w4), oacc, 0, 0, 0);
        }
      }
      #pragma unroll
      for (int p = 0; p < 4; ++p){
        int hd0 = 4*hi + (p & 1)*2 + 8*(p >> 1);
        uint32_t uo = cvtpk(oacc[2*p]*rinv, oacc[2*p + 1]*rinv);
        int c0 = h*16 + hd0;
        *(uint32_t*)(smem + 16384 + pixq*256 + ((c0*2) ^ ((pixq & 7) << 4))) = uo;
      }
    }
  }
  __syncthreads();

  // ---- stage 3: out[cout][pix] = Wproj @ O^T + bias (R3-exact) ----
  {
    int pixl = wv*16 + (lane & 15);
    s16x8 ofr[4];
    #pragma unroll
    for (int ks = 0; ks < 4; ++ks)
      ofr[ks] = *(const s16x8*)(smem + 16384 + pixl*256 +
                 ((ks*64 + (lane >> 4)*16) ^ ((pixl & 7) << 4)));
    int pixg = pix0 + pixl;
    float* outb = out + (size_t)b*128*16384 + pixg;
    #pragma unroll 2
    for (int mtc = 0; mtc < 8; ++mtc){
      f32x4 acc = {0.f, 0.f, 0.f, 0.f};
      #pragma unroll
      for (int ks = 0; ks < 4; ++ks){
        s16x8 wf = *(const s16x8*)(WPB + (mtc*16 + (lane & 15))*128 + ks*32 + 8*(lane >> 4));
        acc = __builtin_amdgcn_mfma_f32_16x16x32_bf16(wf, ofr[ks], acc, 0, 0, 0);
      }
      f32x4 bias = *(const f32x4*)(bproj + mtc*16 + 4*(lane >> 4));
      #pragma unroll
      for (int r = 0; r < 4; ++r){
        int cout = mtc*16 + 4*(lane >> 4) + r;
        outb[(size_t)cout*16384] = acc[r] + bias[r];
      }
    }
  }
}

// ---------------- launcher ----------------
extern "C" void kernel_launch(void* const* d_in, const int* in_sizes, int n_in,
                              void* d_out, int out_size, void* d_ws, size_t ws_size,
                              hipStream_t stream){
  const float* x     = (const float*)d_in[0];
  const float* Wq    = (const float*)d_in[1];
  const float* Wkv   = (const float*)d_in[2];
  const float* Wproj = (const float*)d_in[3];
  const float* bproj = (const float*)d_in[4];
  const float* dww   = (const float*)d_in[5];
  const float* pww   = (const float*)d_in[6];
  const float* lnw   = (const float*)d_in[7];
  const float* lnb   = (const float*)d_in[8];
  char* ws = (char*)d_ws;
  float* out = (float*)d_out;

  kprep<<<196, 256, 0, stream>>>(Wq, Wproj, ws);
  kpool2<<<1024, 256, 0, stream>>>(x, ws);
  kaspp<<<768, 256, 0, stream>>>(dww, pww, Wkv, lnw, lnb, ws);
  kmain<<<2048, 256, 0, stream>>>(ws, x, bproj, out);
}

// Round 7
// 241.632 us; speedup vs baseline: 1.0086x; 1.0086x over previous
//
#include <hip/hip_runtime.h>
#include <stdint.h>

// ---------------- workspace layout (bytes) ----------------
#define OFF_EX   ((size_t)0)           // EX[h][64] f32, 32K
#define OFF_EY   ((size_t)32768)       // EY[c2][128] f32, 32K
#define OFF_EXM  ((size_t)65536)       // EXM[r8][64] f32, 2K
#define OFF_EYM  ((size_t)67584)       // EYM[c8][64] f32, 2K
#define OFF_WQB  ((size_t)69632)       // Wq bf16 [128][128], 32K
#define OFF_WPB  ((size_t)102400)      // Wproj bf16 [128][128], 32K
#define OFF_P8   ((size_t)135168)      // pool8(x only) f32 (8,128,64), 256K
#define OFF_KWS  ((size_t)393216)      // K bf16 (8,8,96,16), 192K
#define OFF_VWS  ((size_t)589824)      // V^T bf16 (8,8,16,96), 192K

typedef __attribute__((ext_vector_type(4)))  float f32x4;
typedef __attribute__((ext_vector_type(16))) float f32x16;
typedef __attribute__((ext_vector_type(8)))  short s16x8;
typedef __attribute__((ext_vector_type(4)))  unsigned int u32x4;

__device__ __forceinline__ uint16_t f2bf(float f){
  uint32_t u = __builtin_bit_cast(uint32_t, f);
  u += 0x7fffu + ((u >> 16) & 1u);
  return (uint16_t)(u >> 16);
}
__device__ __forceinline__ uint32_t cvtpk(float a, float b){
  uint32_t r;
  asm("v_cvt_pk_bf16_f32 %0, %1, %2" : "=v"(r) : "v"(a), "v"(b));
  return r;
}

// ---------------- K0: tables + weight bf16 casts (R5-exact) ----------------
__global__ __launch_bounds__(256) void kprep(const float* __restrict__ Wq,
                                             const float* __restrict__ Wproj,
                                             char* __restrict__ ws){
  int idx = blockIdx.x * 256 + threadIdx.x;
  float* EX = (float*)(ws + OFF_EX);
  float* EY = (float*)(ws + OFF_EY);
  float* EXM = (float*)(ws + OFF_EXM);
  float* EYM = (float*)(ws + OFF_EYM);
  uint16_t* WQB = (uint16_t*)(ws + OFF_WQB);
  uint16_t* WPB = (uint16_t*)(ws + OFF_WPB);
  if (idx < 8192){
    int i = idx >> 6, d = idx & 63;
    float inv = powf(10000.0f, -(float)(d & 31) * (1.0f/32.0f));
    float a = (float)i * inv;
    EX[idx] = (d < 32) ? sinf(a) : cosf(a);
  } else if (idx < 16384){
    int e = idx - 8192;
    int c = e >> 7, j = e & 127;
    float inv = powf(10000.0f, -(float)(c & 31) * (1.0f/32.0f));
    float a = (float)j * inv;
    EY[e] = (c < 32) ? sinf(a) : cosf(a);
  } else if (idx < 32768){
    int e = idx - 16384;
    WQB[e] = f2bf(Wq[e]);
  } else if (idx < 49152){
    int e = idx - 32768;
    WPB[e] = f2bf(Wproj[e]);
  } else if (idx < 49664){
    int e = idx - 49152; int r8 = e >> 6, c = e & 63;
    float inv = powf(10000.0f, -(float)(c & 31) * (1.0f/32.0f));
    float s = 0.f;
    for (int u = 0; u < 16; ++u){
      float a = (float)(r8*16 + u) * inv;
      s += (c < 32) ? sinf(a) : cosf(a);
    }
    EXM[e] = s * (1.0f/16.0f);
  } else if (idx < 50176){
    int e = idx - 49664; int c8 = e >> 6, c2 = e & 63;
    float inv = powf(10000.0f, -(float)(c2 & 31) * (1.0f/32.0f));
    float s = 0.f;
    for (int w = 0; w < 16; ++w){
      float a = (float)(c8*16 + w) * inv;
      s += (c2 < 32) ? sinf(a) : cosf(a);
    }
    EYM[e] = s * (1.0f/16.0f);
  }
}

// ---------------- K1: pool8 of raw x (R5-exact) ----------------
__global__ __launch_bounds__(256) void kpool2(const float* __restrict__ x,
                                              char* __restrict__ ws){
  float* P8 = (float*)(ws + OFF_P8);
  int bx = blockIdx.x;
  int b = bx >> 7, c = bx & 127;
  int t = threadIdx.x, lane = t & 63, wv = t >> 6;
  const float* plane = x + ((size_t)(b*128 + c))*16384;
  float acc[8];
  #pragma unroll
  for (int r = 0; r < 8; ++r) acc[r] = 0.f;
  #pragma unroll
  for (int k = 0; k < 16; ++k){
    f32x4 v = *(const f32x4*)(plane + k*1024 + t*4);
    acc[k >> 1] += (v.x + v.y) + (v.z + v.w);
  }
  __shared__ float wred[4][64];
  int bc = (lane >> 2) & 7;
  #pragma unroll
  for (int br = 0; br < 8; ++br){
    float v = acc[br];
    v += __shfl_xor(v, 1);
    v += __shfl_xor(v, 2);
    v += __shfl_xor(v, 32);
    if ((lane & 3) == 0 && lane < 32) wred[wv][br*8 + bc] = v;
  }
  __syncthreads();
  if (t < 64){
    float s = wred[0][t] + wred[1][t] + wred[2][t] + wred[3][t];
    P8[((size_t)(b*128) + c)*64 + t] = s * (1.0f/256.0f);
  }
}

// ---------------- K2: ASPP branch + LN + GELU + KV (R5-exact) ----------------
__global__ __launch_bounds__(256) void kaspp(const float* __restrict__ dww,
                                             const float* __restrict__ pww,
                                             const float* __restrict__ Wkv,
                                             const float* __restrict__ lnw,
                                             const float* __restrict__ lnb,
                                             char* __restrict__ ws){
  const float* P8  = (const float*)(ws + OFF_P8);
  const float* EXM = (const float*)(ws + OFF_EXM);
  const float* EYM = (const float*)(ws + OFF_EYM);
  uint16_t* KWS = (uint16_t*)(ws + OFF_KWS);
  uint16_t* VWS = (uint16_t*)(ws + OFF_VWS);
  int bx = blockIdx.x;
  int b = bx / 96;
  int pos = bx % 96;
  int t = threadIdx.x;

  if (pos >= 85){
    if (t < 128){
      int m = t >> 4, hd = t & 15;
      KWS[(((size_t)b*8 + m)*96 + pos)*16 + hd] = 0;
      VWS[(((size_t)b*8 + m)*16 + hd)*96 + pos] = 0;
    }
    return;
  }

  int s, si, sj;
  if (pos < 64){ s = 8; si = pos >> 3; sj = pos & 7; }
  else if (pos < 80){ int e = pos - 64; s = 4; si = e >> 2; sj = e & 3; }
  else if (pos < 84){ int e = pos - 80; s = 2; si = e >> 1; sj = e & 1; }
  else { s = 1; si = 0; sj = 0; }

  __shared__ float yl[128], zl[128], red[128], red2[128];

  float acc = 0.f;
  if (t < 128){
    int c = t;
    int bs = 8 / s;
    float y = 0.f;
    const float* p8 = P8 + ((size_t)(b*128) + c)*64;
    float binv = 1.0f / (float)(bs*bs);
    for (int di = -1; di <= 1; ++di)
      for (int dj = -1; dj <= 1; ++dj){
        int a = si + di, bb = sj + dj;
        if (a >= 0 && a < s && bb >= 0 && bb < s){
          float pv = 0.f;
          for (int u = 0; u < bs; ++u)
            for (int v = 0; v < bs; ++v){
              int r8 = a*bs + u, c8 = bb*bs + v;
              float pe = (c < 64) ? EXM[r8*64 + c] : EYM[c8*64 + (c - 64)];
              pv += p8[r8*8 + c8] + pe;
            }
          y += pv * binv * dww[c*9 + (di+1)*3 + (dj+1)];
        }
      }
    yl[t] = y;
  }
  __syncthreads();

  if (t < 128){
    const float* wr = pww + (size_t)t*128;
    for (int cin = 0; cin < 128; ++cin) acc += wr[cin] * yl[cin];
    red[t] = acc; red2[t] = acc*acc;
  }
  __syncthreads();
  for (int off = 64; off >= 1; off >>= 1){
    if (t < off){ red[t] += red[t+off]; red2[t] += red2[t+off]; }
    __syncthreads();
  }
  float mu  = red[0] * (1.0f/128.0f);
  float var = red2[0] * (1.0f/128.0f) - mu*mu;
  if (t < 128){
    float z = (acc - mu) * rsqrtf(var + 1e-5f) * lnw[t] + lnb[t];
    zl[t] = 0.5f * z * (1.0f + erff(z * 0.70710678118654752f));
  }
  __syncthreads();

  {
    float a2 = 0.f;
    const float* wr = Wkv + (size_t)t*128;
    for (int c2 = 0; c2 < 128; ++c2) a2 += wr[c2] * zl[c2];
    uint16_t bv = f2bf(a2);
    if (t < 128){
      int m = t >> 4, hd = t & 15;
      KWS[(((size_t)b*8 + m)*96 + pos)*16 + hd] = bv;
    } else {
      int tt = t - 128;
      int m = tt >> 4, hd = tt & 15;
      VWS[(((size_t)b*8 + m)*16 + hd)*96 + pos] = bv;
    }
  }
}

// ---------------- K3: fused stage + q-GEMM + attention + proj ----------------
// 64 pixels / block, 4 waves, LDS 32 KiB.
// Stage 2 = R5 logic + software-pipelined loads (prefetch next head's K/q;
// V issued post-QK so latency hides under softmax). No min-waves floor.
__global__ __launch_bounds__(256) void kmain(const char* __restrict__ wsc,
                                             const float* __restrict__ x,
                                             const float* __restrict__ bproj,
                                             float* __restrict__ out){
  const char* ws = wsc;
  const uint16_t* WQB = (const uint16_t*)(ws + OFF_WQB);
  const uint16_t* WPB = (const uint16_t*)(ws + OFF_WPB);
  const uint16_t* KWS = (const uint16_t*)(ws + OFF_KWS);
  const uint16_t* VWS = (const uint16_t*)(ws + OFF_VWS);
  const float* EX = (const float*)(ws + OFF_EX);
  const float* EY = (const float*)(ws + OFF_EY);

  __shared__ __align__(16) char smem[32768];
  const int t = threadIdx.x;
  const int lane = t & 63;
  const int wv = t >> 6;
  const int bx = blockIdx.x;
  const int b = bx >> 8;
  const int pix0 = (bx & 255) * 64;
  const int i  = pix0 >> 7;
  const int j0 = pix0 & 127;

  // ---- stage 0: x + PE -> bf16 x-tile [pix][c] swz, two 64-channel halves (R5-exact) ----
  #pragma unroll 1
  for (int half = 0; half < 2; ++half){
    {
      int csub = lane >> 4;
      int p4 = (lane & 15) * 4;
      #pragma unroll
      for (int it = 0; it < 4; ++it){
        int cl = wv*16 + it*4 + csub;
        int c = half*64 + cl;
        f32x4 v = *(const f32x4*)(x + ((size_t)(b*128 + c))*16384 + pix0 + p4);
        if (c < 64){
          float pe = EX[i*64 + c];
          v.x += pe; v.y += pe; v.z += pe; v.w += pe;
        } else {
          f32x4 pe = *(const f32x4*)(EY + (c - 64)*128 + j0 + p4);
          v.x += pe.x; v.y += pe.y; v.z += pe.z; v.w += pe.w;
        }
        *(f32x4*)(smem + 16384 + cl*256 + p4*4) = v;
      }
    }
    __syncthreads();
    {
      const float* tmp = (const float*)(smem + 16384);
      int pix = lane;
      float f[16];
      #pragma unroll
      for (int j = 0; j < 16; ++j) f[j] = tmp[(wv*16 + j)*64 + pix];
      uint32_t u[8];
      #pragma unroll
      for (int j = 0; j < 8; ++j) u[j] = cvtpk(f[2*j], f[2*j+1]);
      #pragma unroll
      for (int g = 0; g < 2; ++g){
        u32x4 w4 = { u[g*4+0], u[g*4+1], u[g*4+2], u[g*4+3] };
        int c0 = half*64 + wv*16 + g*8;
        *(u32x4*)(smem + pix*256 + ((c0*2) ^ ((pix & 7) << 4))) = w4;
      }
    }
    __syncthreads();
  }

  // ---- stage 1: q[pix][nq] = Xpe @ Wq^T (R5-exact) ----
  {
    int pixl = wv*16 + (lane & 15);
    s16x8 xfr[4];
    #pragma unroll
    for (int ks = 0; ks < 4; ++ks)
      xfr[ks] = *(const s16x8*)(smem + pixl*256 +
                 ((ks*64 + (lane >> 4)*16) ^ ((pixl & 7) << 4)));
    __syncthreads();
    #pragma unroll
    for (int nt = 0; nt < 8; ++nt){
      f32x4 acc = {0.f, 0.f, 0.f, 0.f};
      #pragma unroll
      for (int ks = 0; ks < 4; ++ks){
        s16x8 wfr = *(const s16x8*)(WQB + (nt*16 + (lane & 15))*128 + ks*32 + 8*(lane >> 4));
        acc = __builtin_amdgcn_mfma_f32_16x16x32_bf16(wfr, xfr[ks], acc, 0, 0, 0);
      }
      int nq0 = nt*16 + 4*(lane >> 4);
      uint32_t w0 = cvtpk(acc[0], acc[1]);
      uint32_t w1 = cvtpk(acc[2], acc[3]);
      *(uint32_t*)(smem + pixl*256 + ((nq0*2) ^ ((pixl & 7) << 4))) = w0;
      *(uint32_t*)(smem + pixl*256 + (((nq0 + 2)*2) ^ ((pixl & 7) << 4))) = w1;
    }
  }
  __syncthreads();

  // ---- stage 2: attention (R5 math, pipelined loads) ----
  {
    const int ph = wv & 1;
    const int h0 = (wv >> 1) * 4;
    const int hi = lane >> 5;
    const int pixq = ph*32 + (lane & 31);
    const float C1 = 0.36067376022224085f; // 0.25 * log2(e)

    const uint16_t* Kb = KWS + (size_t)(b*8)*1536;
    const uint16_t* Vb = VWS + (size_t)(b*8)*1536;

    // preload head h0's K-frags + q-frag
    s16x8 kfc[3], qfc;
    #pragma unroll
    for (int mt = 0; mt < 3; ++mt)
      kfc[mt] = *(const s16x8*)(Kb + (size_t)h0*1536 + (mt*32 + (lane & 31))*16 + 8*hi);
    qfc = *(const s16x8*)(smem + pixq*256 + ((h0*32 + hi*16) ^ ((pixq & 7) << 4)));

    #pragma unroll 1
    for (int hh = 0; hh < 4; ++hh){
      int h = h0 + hh;

      f32x16 zz;
      #pragma unroll
      for (int r = 0; r < 16; ++r) zz[r] = 0.f;
      f32x16 sa[3];
      #pragma unroll
      for (int mt = 0; mt < 3; ++mt)
        sa[mt] = __builtin_amdgcn_mfma_f32_32x32x16_bf16(kfc[mt], qfc, zz, 0, 0, 0);

      // issue this head's V loads + next head's K/q loads; they land under softmax
      s16x8 vf[6];
      #pragma unroll
      for (int kc = 0; kc < 6; ++kc)
        vf[kc] = *(const s16x8*)(Vb + (size_t)h*1536 + (lane & 15)*96 + kc*16 + 8*hi);
      s16x8 kfn[3], qfn;
      if (hh < 3){
        #pragma unroll
        for (int mt = 0; mt < 3; ++mt)
          kfn[mt] = *(const s16x8*)(Kb + (size_t)(h+1)*1536 + (mt*32 + (lane & 31))*16 + 8*hi);
        qfn = *(const s16x8*)(smem + pixq*256 + (((h+1)*32 + hi*16) ^ ((pixq & 7) << 4)));
      }

      // softmax over kv (R5-exact; invalid kv scores are exactly 0 -> mx >= 0 safe)
      float mx = 0.f;
      #pragma unroll
      for (int r = 0; r < 16; ++r){
        mx = fmaxf(mx, sa[0][r]);
        mx = fmaxf(mx, sa[1][r]);
        mx = fmaxf(mx, sa[2][r]);
      }
      mx = fmaxf(mx, __shfl_xor(mx, 32));
      float sum = 0.f;
      #pragma unroll
      for (int r = 0; r < 16; ++r){
        float p0 = exp2f((sa[0][r] - mx)*C1); sa[0][r] = p0; sum += p0;
        float p1 = exp2f((sa[1][r] - mx)*C1); sa[1][r] = p1; sum += p1;
        int kvb = (r & 3) + 8*(r >> 2) + 4*hi;
        float p2 = (64 + kvb < 85) ? exp2f((sa[2][r] - mx)*C1) : 0.f;
        sa[2][r] = p2; sum += p2;
      }
      sum += __shfl_xor(sum, 32);
      float rinv = 1.0f / sum;

      // PV: pack P (unnormalized) via cvt_pk + one lane^32 exchange (R5-exact)
      f32x16 oacc = zz;
      #pragma unroll
      for (int mt = 0; mt < 3; ++mt){
        uint32_t u0[4], u1[4];
        #pragma unroll
        for (int q = 0; q < 4; ++q){
          u0[q] = cvtpk(sa[mt][4*q + 0], sa[mt][4*q + 1]);
          u1[q] = cvtpk(sa[mt][4*q + 2], sa[mt][4*q + 3]);
        }
        #pragma unroll
        for (int c2 = 0; c2 < 2; ++c2){
          uint32_t s0 = hi ? u0[2*c2] : u0[2*c2 + 1];
          uint32_t s1 = hi ? u1[2*c2] : u1[2*c2 + 1];
          uint32_t r0 = (uint32_t)__shfl_xor((int)s0, 32);
          uint32_t r1 = (uint32_t)__shfl_xor((int)s1, 32);
          u32x4 w4;
          w4.x = hi ? r0 : u0[2*c2];
          w4.y = hi ? r1 : u1[2*c2];
          w4.z = hi ? u0[2*c2 + 1] : r0;
          w4.w = hi ? u1[2*c2 + 1] : r1;
          oacc = __builtin_amdgcn_mfma_f32_32x32x16_bf16(
                   vf[mt*2 + c2], __builtin_bit_cast(s16x8, w4), oacc, 0, 0, 0);
        }
      }
      #pragma unroll
      for (int p = 0; p < 4; ++p){
        int hd0 = 4*hi + (p & 1)*2 + 8*(p >> 1);
        uint32_t uo = cvtpk(oacc[2*p]*rinv, oacc[2*p + 1]*rinv);
        int c0 = h*16 + hd0;
        *(uint32_t*)(smem + 16384 + pixq*256 + ((c0*2) ^ ((pixq & 7) << 4))) = uo;
      }

      // rotate prefetched frags
      if (hh < 3){
        #pragma unroll
        for (int mt = 0; mt < 3; ++mt) kfc[mt] = kfn[mt];
        qfc = qfn;
      }
    }
  }
  __syncthreads();

  // ---- stage 3: out[cout][pix] = Wproj @ O^T + bias (R5-exact) ----
  {
    int pixl = wv*16 + (lane & 15);
    s16x8 ofr[4];
    #pragma unroll
    for (int ks = 0; ks < 4; ++ks)
      ofr[ks] = *(const s16x8*)(smem + 16384 + pixl*256 +
                 ((ks*64 + (lane >> 4)*16) ^ ((pixl & 7) << 4)));
    int pixg = pix0 + pixl;
    float* outb = out + (size_t)b*128*16384 + pixg;
    #pragma unroll 2
    for (int mtc = 0; mtc < 8; ++mtc){
      f32x4 acc = {0.f, 0.f, 0.f, 0.f};
      #pragma unroll
      for (int ks = 0; ks < 4; ++ks){
        s16x8 wf = *(const s16x8*)(WPB + (mtc*16 + (lane & 15))*128 + ks*32 + 8*(lane >> 4));
        acc = __builtin_amdgcn_mfma_f32_16x16x32_bf16(wf, ofr[ks], acc, 0, 0, 0);
      }
      f32x4 bias = *(const f32x4*)(bproj + mtc*16 + 4*(lane >> 4));
      #pragma unroll
      for (int r = 0; r < 4; ++r){
        int cout = mtc*16 + 4*(lane >> 4) + r;
        outb[(size_t)cout*16384] = acc[r] + bias[r];
      }
    }
  }
}

// ---------------- launcher ----------------
extern "C" void kernel_launch(void* const* d_in, const int* in_sizes, int n_in,
                              void* d_out, int out_size, void* d_ws, size_t ws_size,
                              hipStream_t stream){
  const float* x     = (const float*)d_in[0];
  const float* Wq    = (const float*)d_in[1];
  const float* Wkv   = (const float*)d_in[2];
  const float* Wproj = (const float*)d_in[3];
  const float* bproj = (const float*)d_in[4];
  const float* dww   = (const float*)d_in[5];
  const float* pww   = (const float*)d_in[6];
  const float* lnw   = (const float*)d_in[7];
  const float* lnb   = (const float*)d_in[8];
  char* ws = (char*)d_ws;
  float* out = (float*)d_out;

  kprep<<<196, 256, 0, stream>>>(Wq, Wproj, ws);
  kpool2<<<1024, 256, 0, stream>>>(x, ws);
  kaspp<<<768, 256, 0, stream>>>(dww, pww, Wkv, lnw, lnb, ws);
  kmain<<<2048, 256, 0, stream>>>(ws, x, bproj, out);
}